// Round 15
// baseline (453.865 us; speedup 1.0000x reference)
//
#include <hip/hip_runtime.h>
#include <math.h>

#define NB   64
#define NL   512
#define ND   768
#define NP   128
#define NHID 1024
#define NTOK (NB * NL)
#define TPW  4   // tokens per wave

typedef float f4 __attribute__((ext_vector_type(4)));

// One 64-lane wave per FOUR tokens. Chunked-contiguous lane layout per token:
//   chunk j (j=0..3): elements [j*256 + lane*4, +4)
//   chunks 0-2 = token path (768), chunk 3 = pos path (256)
// Every load/store instruction covers 1KB contiguous per wave (full 64B
// sectors -> NT stores can't write-amplify; R2 lesson). Single butterfly
// reduces 8 independent chains (sum+sumsq x 4 tokens) for all tokens.
__global__ __launch_bounds__(256, 4)
void molt_embed_ln(
    const int*   __restrict__ input_ids,
    const int*   __restrict__ token_type_ids,
    const int*   __restrict__ pos_embed_ids,
    const float* __restrict__ lp_embeds,
    const int*   __restrict__ p_ring,
    const int*   __restrict__ p_charge,
    const int*   __restrict__ p_hyb,
    const int*   __restrict__ p_chir,
    const int*   __restrict__ p_arom,
    const int*   __restrict__ p_conj,
    const int*   __restrict__ p_stereo,
    const float* __restrict__ mol_features,
    const float* __restrict__ target_values,
    const float* __restrict__ emb_table,
    const float* __restrict__ type_table,
    const float* __restrict__ ring_tab,
    const float* __restrict__ charge_tab,
    const float* __restrict__ hyb_tab,
    const float* __restrict__ chir_tab,
    const float* __restrict__ arom_tab,
    const float* __restrict__ conj_tab,
    const float* __restrict__ stereo_tab,
    const float* __restrict__ ln_gamma,
    const float* __restrict__ ln_beta,
    float*       __restrict__ out)
{
    const int lane = threadIdx.x & 63;
    int t0 = (blockIdx.x << 4) + ((threadIdx.x >> 6) << 2);
    t0 = __builtin_amdgcn_readfirstlane(t0);   // wave-uniform -> SGPR index loads
    const int b = t0 >> 9;                     // 4-token groups never cross a batch row
    const int h = lane << 2;                   // 0..252, 16B-aligned

    f4 v[TPW][4];

    #pragma unroll
    for (int tk = 0; tk < TPW; ++tk) {
        const int t    = t0 + tk;
        const int id   = input_ids[t];
        const int tt   = token_type_ids[t];
        const int ir   = p_ring[t];
        const int ic   = p_charge[t];
        const int ihy  = p_hyb[t];
        const int ichr = p_chir[t];
        const int ia   = p_arom[t];
        const int icj  = p_conj[t];
        const int ist  = p_stereo[t];

        float scale = 1.0f;
        if (tt == 5)      scale += mol_features[t];   // FEAT
        else if (tt == 6) scale += target_values[t];  // TGT

        const float* e  = emb_table  + (size_t)id   * ND;
        const float* ty = type_table + (size_t)tt   * ND;
        const float* r  = ring_tab   + (size_t)ir   * ND;
        const float* c  = charge_tab + (size_t)ic   * ND;
        const float* hy = hyb_tab    + (size_t)ihy  * ND;
        const float* ch = chir_tab   + (size_t)ichr * ND;
        const float* ar = arom_tab   + (size_t)ia   * ND;
        const float* cj = conj_tab   + (size_t)icj  * ND;
        const float* st = stereo_tab + (size_t)ist  * ND;

        #pragma unroll
        for (int j = 0; j < 3; ++j) {
            const int off = j * 256 + h;       // 1KB contiguous per wave per instr
            f4 s = *(const f4*)(ty + off) + *(const f4*)(r  + off)
                 + *(const f4*)(c  + off) + *(const f4*)(hy + off)
                 + *(const f4*)(ch + off) + *(const f4*)(ar + off)
                 + *(const f4*)(cj + off) + *(const f4*)(st + off);
            v[tk][j] = *(const f4*)(e + off) * scale + s;
        }

        const int kk  = lane >> 5;             // K index (0/1)
        const int pp  = (lane & 31) << 2;      // 0..124
        const int pid = pos_embed_ids[(t << 1) + kk];
        f4 a = *(const f4*)(lp_embeds + ((size_t)(b * NL + pid)) * NP + pp);
        #pragma unroll
        for (int k = 0; k < 4; ++k) a[k] = (a[k] == a[k]) ? a[k] : 0.0f;
        v[tk][3] = a;
    }

    // ---- single-pass sum + sumsq: 8 independent butterfly chains ----
    float s[TPW], p[TPW];
    #pragma unroll
    for (int tk = 0; tk < TPW; ++tk) {
        float ss = 0.f, pp2 = 0.f;
        #pragma unroll
        for (int j = 0; j < 4; ++j) {
            #pragma unroll
            for (int k = 0; k < 4; ++k) {
                float a = v[tk][j][k];
                ss += a; pp2 += a * a;
            }
        }
        s[tk] = ss; p[tk] = pp2;
    }
    #pragma unroll
    for (int off = 32; off; off >>= 1) {
        #pragma unroll
        for (int tk = 0; tk < TPW; ++tk) {
            s[tk] += __shfl_xor(s[tk], off, 64);
            p[tk] += __shfl_xor(p[tk], off, 64);
        }
    }
    float mean[TPW], inv[TPW];
    #pragma unroll
    for (int tk = 0; tk < TPW; ++tk) {
        mean[tk] = s[tk] * (1.0f / (float)NHID);
        float var = fmaxf(p[tk] * (1.0f / (float)NHID) - mean[tk] * mean[tk], 0.0f);
        inv[tk] = 1.0f / sqrtf(var + 1e-12f);
    }

    // ---- write: 1KB-contiguous NT stores; gamma/beta amortized over 4 tokens ----
    #pragma unroll
    for (int j = 0; j < 4; ++j) {
        const int off = j * 256 + h;
        f4 g  = *(const f4*)(ln_gamma + off);
        f4 be = *(const f4*)(ln_beta  + off);
        #pragma unroll
        for (int tk = 0; tk < TPW; ++tk) {
            f4 q = (v[tk][j] - mean[tk]) * inv[tk] * g + be;
            __builtin_nontemporal_store(q, (f4*)(out + (size_t)(t0 + tk) * NHID + off));
        }
    }
}

extern "C" void kernel_launch(void* const* d_in, const int* in_sizes, int n_in,
                              void* d_out, int out_size, void* d_ws, size_t ws_size,
                              hipStream_t stream) {
    (void)in_sizes; (void)n_in; (void)out_size; (void)d_ws; (void)ws_size;
    molt_embed_ln<<<NTOK / (4 * TPW), 256, 0, stream>>>(
        (const int*)d_in[0],  (const int*)d_in[1],  (const int*)d_in[2],
        (const float*)d_in[3],
        (const int*)d_in[4],  (const int*)d_in[5],  (const int*)d_in[6],
        (const int*)d_in[7],  (const int*)d_in[8],  (const int*)d_in[9],
        (const int*)d_in[10],
        (const float*)d_in[11], (const float*)d_in[12],
        (const float*)d_in[13], (const float*)d_in[14], (const float*)d_in[15],
        (const float*)d_in[16], (const float*)d_in[17], (const float*)d_in[18],
        (const float*)d_in[19], (const float*)d_in[20], (const float*)d_in[21],
        (const float*)d_in[22], (const float*)d_in[23],
        (float*)d_out);
}

// Round 16
// 322.504 us; speedup vs baseline: 1.4073x; 1.4073x over previous
//
#include <hip/hip_runtime.h>
#include <math.h>

#define NB   64
#define NL   512
#define ND   768
#define NP   128
#define NHID 1024
#define NTOK (NB * NL)
#define TPW  4   // tokens per wave

typedef float f4 __attribute__((ext_vector_type(4)));

// One 64-lane wave per FOUR tokens. Chunked-contiguous lane layout per token:
//   chunk j (j=0..3): elements [j*256 + lane*4, +4)
//   chunks 0-2 = token path (768), chunk 3 = pos path (256)
// Every load/store instruction covers 1KB contiguous per wave (full 64B
// sectors -> NT stores can't write-amplify; R2 lesson).
// R15 lesson: __launch_bounds__(256,4) caps VGPR at 64 -> v[4][4] spills to
// scratch -> 4.4x write / 5.8x fetch amplification, 305us. Use (256,2):
// VGPR cap 256, ~125 live regs fit spill-free; per-wave MLP > occupancy.
__global__ __launch_bounds__(256, 2)
void molt_embed_ln(
    const int*   __restrict__ input_ids,
    const int*   __restrict__ token_type_ids,
    const int*   __restrict__ pos_embed_ids,
    const float* __restrict__ lp_embeds,
    const int*   __restrict__ p_ring,
    const int*   __restrict__ p_charge,
    const int*   __restrict__ p_hyb,
    const int*   __restrict__ p_chir,
    const int*   __restrict__ p_arom,
    const int*   __restrict__ p_conj,
    const int*   __restrict__ p_stereo,
    const float* __restrict__ mol_features,
    const float* __restrict__ target_values,
    const float* __restrict__ emb_table,
    const float* __restrict__ type_table,
    const float* __restrict__ ring_tab,
    const float* __restrict__ charge_tab,
    const float* __restrict__ hyb_tab,
    const float* __restrict__ chir_tab,
    const float* __restrict__ arom_tab,
    const float* __restrict__ conj_tab,
    const float* __restrict__ stereo_tab,
    const float* __restrict__ ln_gamma,
    const float* __restrict__ ln_beta,
    float*       __restrict__ out)
{
    const int lane = threadIdx.x & 63;
    int t0 = (blockIdx.x << 4) + ((threadIdx.x >> 6) << 2);
    t0 = __builtin_amdgcn_readfirstlane(t0);   // wave-uniform -> SGPR index loads
    const int b = t0 >> 9;                     // 4-token groups never cross a batch row
    const int h = lane << 2;                   // 0..252, 16B-aligned

    f4 v[TPW][4];

    #pragma unroll
    for (int tk = 0; tk < TPW; ++tk) {
        const int t    = t0 + tk;
        const int id   = input_ids[t];
        const int tt   = token_type_ids[t];
        const int ir   = p_ring[t];
        const int ic   = p_charge[t];
        const int ihy  = p_hyb[t];
        const int ichr = p_chir[t];
        const int ia   = p_arom[t];
        const int icj  = p_conj[t];
        const int ist  = p_stereo[t];

        float scale = 1.0f;
        if (tt == 5)      scale += mol_features[t];   // FEAT
        else if (tt == 6) scale += target_values[t];  // TGT

        const float* e  = emb_table  + (size_t)id   * ND;
        const float* ty = type_table + (size_t)tt   * ND;
        const float* r  = ring_tab   + (size_t)ir   * ND;
        const float* c  = charge_tab + (size_t)ic   * ND;
        const float* hy = hyb_tab    + (size_t)ihy  * ND;
        const float* ch = chir_tab   + (size_t)ichr * ND;
        const float* ar = arom_tab   + (size_t)ia   * ND;
        const float* cj = conj_tab   + (size_t)icj  * ND;
        const float* st = stereo_tab + (size_t)ist  * ND;

        #pragma unroll
        for (int j = 0; j < 3; ++j) {
            const int off = j * 256 + h;       // 1KB contiguous per wave per instr
            f4 s = *(const f4*)(ty + off) + *(const f4*)(r  + off)
                 + *(const f4*)(c  + off) + *(const f4*)(hy + off)
                 + *(const f4*)(ch + off) + *(const f4*)(ar + off)
                 + *(const f4*)(cj + off) + *(const f4*)(st + off);
            v[tk][j] = *(const f4*)(e + off) * scale + s;
        }

        const int kk  = lane >> 5;             // K index (0/1)
        const int pp  = (lane & 31) << 2;      // 0..124
        const int pid = pos_embed_ids[(t << 1) + kk];
        f4 a = *(const f4*)(lp_embeds + ((size_t)(b * NL + pid)) * NP + pp);
        #pragma unroll
        for (int k = 0; k < 4; ++k) a[k] = (a[k] == a[k]) ? a[k] : 0.0f;
        v[tk][3] = a;
    }

    // ---- single-pass sum + sumsq: 8 independent butterfly chains ----
    float s[TPW], p[TPW];
    #pragma unroll
    for (int tk = 0; tk < TPW; ++tk) {
        float ss = 0.f, pp2 = 0.f;
        #pragma unroll
        for (int j = 0; j < 4; ++j) {
            #pragma unroll
            for (int k = 0; k < 4; ++k) {
                float a = v[tk][j][k];
                ss += a; pp2 += a * a;
            }
        }
        s[tk] = ss; p[tk] = pp2;
    }
    #pragma unroll
    for (int off = 32; off; off >>= 1) {
        #pragma unroll
        for (int tk = 0; tk < TPW; ++tk) {
            s[tk] += __shfl_xor(s[tk], off, 64);
            p[tk] += __shfl_xor(p[tk], off, 64);
        }
    }
    float mean[TPW], inv[TPW];
    #pragma unroll
    for (int tk = 0; tk < TPW; ++tk) {
        mean[tk] = s[tk] * (1.0f / (float)NHID);
        float var = fmaxf(p[tk] * (1.0f / (float)NHID) - mean[tk] * mean[tk], 0.0f);
        inv[tk] = 1.0f / sqrtf(var + 1e-12f);
    }

    // ---- write: 1KB-contiguous NT stores; gamma/beta amortized over 4 tokens ----
    #pragma unroll
    for (int j = 0; j < 4; ++j) {
        const int off = j * 256 + h;
        f4 g  = *(const f4*)(ln_gamma + off);
        f4 be = *(const f4*)(ln_beta  + off);
        #pragma unroll
        for (int tk = 0; tk < TPW; ++tk) {
            f4 q = (v[tk][j] - mean[tk]) * inv[tk] * g + be;
            __builtin_nontemporal_store(q, (f4*)(out + (size_t)(t0 + tk) * NHID + off));
        }
    }
}

extern "C" void kernel_launch(void* const* d_in, const int* in_sizes, int n_in,
                              void* d_out, int out_size, void* d_ws, size_t ws_size,
                              hipStream_t stream) {
    (void)in_sizes; (void)n_in; (void)out_size; (void)d_ws; (void)ws_size;
    molt_embed_ln<<<NTOK / (4 * TPW), 256, 0, stream>>>(
        (const int*)d_in[0],  (const int*)d_in[1],  (const int*)d_in[2],
        (const float*)d_in[3],
        (const int*)d_in[4],  (const int*)d_in[5],  (const int*)d_in[6],
        (const int*)d_in[7],  (const int*)d_in[8],  (const int*)d_in[9],
        (const int*)d_in[10],
        (const float*)d_in[11], (const float*)d_in[12],
        (const float*)d_in[13], (const float*)d_in[14], (const float*)d_in[15],
        (const float*)d_in[16], (const float*)d_in[17], (const float*)d_in[18],
        (const float*)d_in[19], (const float*)d_in[20], (const float*)d_in[21],
        (const float*)d_in[22], (const float*)d_in[23],
        (float*)d_out);
}